// Round 17
// 446.506 us; speedup vs baseline: 7.7725x; 1.0688x over previous
//
#include <hip/hip_runtime.h>
#include <math.h>

#define N_NODES 100000
#define N_EDGES 600000
#define N_GRAPHS 4096
#define DMAX 32         // static CSR slot capacity (P(deg>=32) ~ 1e-13/node)
#define EOUT_BLK 512    // edge_out grid (LDS-binned, scratch copies)
#define UPD_BLK 2048    // update_h grid (grid-stride, amortized BN2 finalize)

typedef __attribute__((ext_vector_type(8))) short short8v;   // 8 bf16 (4 VGPR)
typedef __attribute__((ext_vector_type(4))) float f32x4;

// fp32 pair -> packed bf16 (RNE) via the HW instruction
__device__ __forceinline__ unsigned int pack2(float a, float b) {
    unsigned int r;
    asm("v_cvt_pk_bf16_f32 %0, %1, %2" : "=v"(r) : "v"(a), "v"(b));
    return r;
}
__device__ __forceinline__ unsigned short bf16_rne(float f) {
    unsigned int r;
    asm("v_cvt_pk_bf16_f32 %0, %1, %2" : "=v"(r) : "v"(f), "v"(f));
    return (unsigned short)r;
}
__device__ __forceinline__ float bf2f(unsigned short u) {
    return __uint_as_float(((unsigned int)u) << 16);
}

// ------ merged front: three INDEPENDENT one-time jobs in one dispatch:
//   blocks [0,25000)      atom encoder (wave/node, scalarized x-row)
//   blocks [25000,27344)  static-slot CSR fill (cnt = counter AND cursor)
//   blocks [27344,28880)  weight pre-swizzle + combined bond table
__global__ void k_front(const int* __restrict__ x, const float* __restrict__ at,
                        unsigned short* __restrict__ hb,
                        const int* __restrict__ ei, const int* __restrict__ ea,
                        int* __restrict__ cnt, int* __restrict__ csr_pack,
                        const float* __restrict__ W1, const float* __restrict__ W2,
                        const float* __restrict__ bt,
                        unsigned short* __restrict__ Bp1, unsigned short* __restrict__ Bp2,
                        unsigned short* __restrict__ ct) {
    if (blockIdx.x < 25000) {
        int lane = threadIdx.x & 63;
        int n = blockIdx.x * 4 + (threadIdx.x >> 6);
        n = __builtin_amdgcn_readfirstlane(n);
        const int* xr = x + n * 9;
        float sx = 0.f, sy = 0.f;
#pragma unroll
        for (int f = 0; f < 9; ++f) {
            int v = __builtin_amdgcn_readfirstlane(xr[f]);
            float2 t = ((const float2*)(at + (f * 100 + v) * 128))[lane];
            sx += t.x;
            sy += t.y;
        }
        ((unsigned int*)(hb + ((size_t)n << 7)))[lane] = pack2(sx, sy);
    } else if (blockIdx.x < 27344) {
        int e = (blockIdx.x - 25000) * 256 + threadIdx.x;
        if (e < N_EDGES) {
            int c = ei[N_EDGES + e];
            int pos = atomicAdd(&cnt[c], 1);
            if (pos < DMAX) {
                int attr = ea[e * 3] * 64 + ea[e * 3 + 1] * 8 + ea[e * 3 + 2];
                csr_pack[((size_t)c << 5) + pos] = (ei[e] << 9) | attr;
            }
        }
    } else {
        int pb = blockIdx.x - 27344;
        if (pb < 768) {
            int idx = pb * 256 + threadIdx.x;
            if (idx < 3 * 128 * 256) {
                int l = idx >> 15, r = idx & 32767;
                int k = r >> 8, j = r & 255;
                float v = W1[(size_t)l * 32768 + k * 256 + j];
                Bp1[(size_t)l * 32768 +
                    (((k >> 5) * 4 + ((k >> 3) & 3)) * 256 + j) * 8 + (k & 7)] = bf16_rne(v);
            } else if (idx < 6 * 128 * 256) {
                int t = idx - 98304;
                int l = t >> 15, r = t & 32767;
                int k = r >> 7, j = r & 127;
                float v = W2[(size_t)l * 32768 + k * 128 + j];
                Bp2[(size_t)l * 32768 +
                    (((k >> 5) * 4 + ((k >> 3) & 3)) * 128 + j) * 8 + (k & 7)] = bf16_rne(v);
            }
        } else {
            int idx = (pb - 768) * 256 + threadIdx.x;
            if (idx >= 3 * 512 * 128) return;
            int d = idx & 127;
            int c = (idx >> 7) & 511;
            int l = idx >> 16;
            const float* base = bt + (size_t)l * 3072;
            float v = base[(c >> 6) * 128 + d] + base[1024 + ((c >> 3) & 7) * 128 + d] +
                      base[2048 + (c & 7) * 128 + d];
            ct[idx] = bf16_rne(v);
        }
    }
}

// ---------------------------- gather-aggregate: z = (1+eps)*h + sum relu(msg)
// wave per node; static-slot CSR (base n*32, deg from cnt); scalarized index
// stream; self-load hoisted; 4/2/1 tail
#define EDGE2(uu, cc)                                                          \
    {                                                                          \
        ax += fmaxf(bf2f((unsigned short)((uu) & 0xffffu)) +                   \
                    bf2f((unsigned short)((cc) & 0xffffu)), 0.f);              \
        ay += fmaxf(bf2f((unsigned short)((uu) >> 16)) +                       \
                    bf2f((unsigned short)((cc) >> 16)), 0.f);                  \
    }

__global__ void k_gather(const unsigned short* __restrict__ hb,
                         const int* __restrict__ csr_pack, const int* __restrict__ cnt,
                         const unsigned short* __restrict__ ct,
                         const float* __restrict__ eps, int l,
                         unsigned short* __restrict__ zb) {
    int lane = threadIdx.x & 63;
    int n = blockIdx.x * 4 + (threadIdx.x >> 6);
    if (n >= N_NODES) return;
    n = __builtin_amdgcn_readfirstlane(n);
    int deg = __builtin_amdgcn_readfirstlane(cnt[n]);
    deg = min(deg, DMAX);
    const int* row = csr_pack + ((size_t)n << 5);
    unsigned int un = ((const unsigned int*)(hb + ((size_t)n << 7)))[lane];
    float ax = 0.f, ay = 0.f;
    int i = 0;
    for (; i + 4 <= deg; i += 4) {
        int rc0 = __builtin_amdgcn_readfirstlane(row[i]);
        int rc1 = __builtin_amdgcn_readfirstlane(row[i + 1]);
        int rc2 = __builtin_amdgcn_readfirstlane(row[i + 2]);
        int rc3 = __builtin_amdgcn_readfirstlane(row[i + 3]);
        unsigned int u0 = ((const unsigned int*)(hb + ((size_t)(rc0 >> 9) << 7)))[lane];
        unsigned int u1 = ((const unsigned int*)(hb + ((size_t)(rc1 >> 9) << 7)))[lane];
        unsigned int u2 = ((const unsigned int*)(hb + ((size_t)(rc2 >> 9) << 7)))[lane];
        unsigned int u3 = ((const unsigned int*)(hb + ((size_t)(rc3 >> 9) << 7)))[lane];
        unsigned int c0 = ((const unsigned int*)(ct + ((rc0 & 511) << 7)))[lane];
        unsigned int c1 = ((const unsigned int*)(ct + ((rc1 & 511) << 7)))[lane];
        unsigned int c2 = ((const unsigned int*)(ct + ((rc2 & 511) << 7)))[lane];
        unsigned int c3 = ((const unsigned int*)(ct + ((rc3 & 511) << 7)))[lane];
        EDGE2(u0, c0); EDGE2(u1, c1); EDGE2(u2, c2); EDGE2(u3, c3);
    }
    if (i + 2 <= deg) {
        int rc0 = __builtin_amdgcn_readfirstlane(row[i]);
        int rc1 = __builtin_amdgcn_readfirstlane(row[i + 1]);
        unsigned int u0 = ((const unsigned int*)(hb + ((size_t)(rc0 >> 9) << 7)))[lane];
        unsigned int u1 = ((const unsigned int*)(hb + ((size_t)(rc1 >> 9) << 7)))[lane];
        unsigned int c0 = ((const unsigned int*)(ct + ((rc0 & 511) << 7)))[lane];
        unsigned int c1 = ((const unsigned int*)(ct + ((rc1 & 511) << 7)))[lane];
        EDGE2(u0, c0); EDGE2(u1, c1);
        i += 2;
    }
    if (i < deg) {
        int rc0 = __builtin_amdgcn_readfirstlane(row[i]);
        unsigned int u0 = ((const unsigned int*)(hb + ((size_t)(rc0 >> 9) << 7)))[lane];
        unsigned int c0 = ((const unsigned int*)(ct + ((rc0 & 511) << 7)))[lane];
        EDGE2(u0, c0);
    }
    float el = 1.0f + eps[l];
    float zx = fmaf(el, bf2f((unsigned short)(un & 0xffffu)), ax);
    float zy = fmaf(el, bf2f((unsigned short)(un >> 16)), ay);
    ((unsigned int*)(zb + ((size_t)n << 7)))[lane] = pack2(zx, zy);
}

// --------------------- GEMM1 (MFMA, swapped operands -> (z@W1)^T fragments)
// stats partials go to 16 spread copies (sl[(bid&15)*768 + ...])
__global__ __launch_bounds__(256) void k_gemm1(
    const unsigned short* __restrict__ zb, const unsigned short* __restrict__ Bp,
    const float* __restrict__ bias, unsigned short* __restrict__ tb,
    float* __restrict__ sl) {
    __shared__ unsigned short As[8192] __attribute__((aligned(16)));  // 16 KB
    int n0 = blockIdx.x * 64;
#pragma unroll
    for (int s = 0; s < 4; ++s) {
        int i = threadIdx.x + s * 256;            // 16B unit; 64 rows x 16 units
        int r = i >> 4, k8 = i & 15;
        short8v v = (short8v)(short)0;
        if (n0 + r < N_NODES) v = ((const short8v*)(zb + (size_t)(n0 + r) * 128))[k8];
        int frag = (r >> 4) * 16 + k8;
        int off = (frag * 128 + (r & 15) * 8) ^ ((k8 & 7) << 3);
        *(short8v*)(&As[off]) = v;
    }
    __syncthreads();
    int lane = threadIdx.x & 63;
    int wid = threadIdx.x >> 6;
    int l15 = lane & 15, kg = lane >> 4;
    int colbase = wid * 64;
    f32x4 acc[4][4];  // [rb][cf]
#pragma unroll
    for (int a = 0; a < 4; ++a)
#pragma unroll
        for (int b = 0; b < 4; ++b) acc[a][b] = (f32x4)(0.f);
#pragma unroll
    for (int k4 = 0; k4 < 4; ++k4) {
        short8v af[4], bf[4];
#pragma unroll
        for (int rb = 0; rb < 4; ++rb)
            af[rb] = *(const short8v*)(&As[((rb * 16 + k4 * 4 + kg) * 128 + l15 * 8) ^
                                           (((k4 * 4 + kg) & 7) << 3)]);
#pragma unroll
        for (int cf = 0; cf < 4; ++cf)
            bf[cf] = *(const short8v*)(Bp + ((k4 * 4 + kg) * 256 + colbase + cf * 16 + l15) * 8);
#pragma unroll
        for (int rb = 0; rb < 4; ++rb)
#pragma unroll
            for (int cf = 0; cf < 4; ++cf)
                acc[rb][cf] = __builtin_amdgcn_mfma_f32_16x16x32_bf16(bf[cf], af[rb],
                                                                      acc[rb][cf], 0, 0, 0);
    }
    float s4[4][4], q4[4][4];
#pragma unroll
    for (int cf = 0; cf < 4; ++cf)
#pragma unroll
        for (int r = 0; r < 4; ++r) { s4[cf][r] = 0.f; q4[cf][r] = 0.f; }
#pragma unroll
    for (int cf = 0; cf < 4; ++cf) {
        int j0 = colbase + cf * 16 + kg * 4;
        float4 b4 = *(const float4*)(bias + j0);
#pragma unroll
        for (int rb = 0; rb < 4; ++rb) {
            int gr = n0 + rb * 16 + l15;
            if (gr < N_NODES) {
                float v0 = acc[rb][cf][0] + b4.x;
                float v1 = acc[rb][cf][1] + b4.y;
                float v2 = acc[rb][cf][2] + b4.z;
                float v3 = acc[rb][cf][3] + b4.w;
                uint2 st;
                st.x = pack2(v0, v1);
                st.y = pack2(v2, v3);
                *(uint2*)(tb + (size_t)gr * 256 + j0) = st;
                s4[cf][0] += v0; q4[cf][0] += v0 * v0;
                s4[cf][1] += v1; q4[cf][1] += v1 * v1;
                s4[cf][2] += v2; q4[cf][2] += v2 * v2;
                s4[cf][3] += v3; q4[cf][3] += v3 * v3;
            }
        }
    }
    float* stats = sl + (size_t)(blockIdx.x & 15) * 768;
    float* part = (float*)As;
    __syncthreads();
#pragma unroll
    for (int cf = 0; cf < 4; ++cf)
#pragma unroll
        for (int r = 0; r < 4; ++r)
            part[(colbase + cf * 16 + kg * 4 + r) * 16 + l15] = s4[cf][r];
    __syncthreads();
    {
        int j = threadIdx.x;
        const float4* pr = (const float4*)(part + j * 16);
        float4 a0 = pr[0], a1 = pr[1], a2 = pr[2], a3 = pr[3];
        float s = a0.x + a0.y + a0.z + a0.w + a1.x + a1.y + a1.z + a1.w +
                  a2.x + a2.y + a2.z + a2.w + a3.x + a3.y + a3.z + a3.w;
        atomicAdd(&stats[j], s);
    }
    __syncthreads();
#pragma unroll
    for (int cf = 0; cf < 4; ++cf)
#pragma unroll
        for (int r = 0; r < 4; ++r)
            part[(colbase + cf * 16 + kg * 4 + r) * 16 + l15] = q4[cf][r];
    __syncthreads();
    {
        int j = threadIdx.x;
        const float4* pr = (const float4*)(part + j * 16);
        float4 a0 = pr[0], a1 = pr[1], a2 = pr[2], a3 = pr[3];
        float s = a0.x + a0.y + a0.z + a0.w + a1.x + a1.y + a1.z + a1.w +
                  a2.x + a2.y + a2.z + a2.w + a3.x + a3.y + a3.z + a3.w;
        atomicAdd(&stats[256 + j], s);
    }
}

// ------- GEMM2 (MFMA, swapped): u = relu(BN1(t))@W2 + b2, fused BN2 stats
// BN1 finalize done in-block: sum 16 spread copies -> LDS -> regs
__global__ __launch_bounds__(256) void k_gemm2(
    const unsigned short* __restrict__ tb, const unsigned short* __restrict__ Bp,
    const float* __restrict__ sl, const float* __restrict__ g1,
    const float* __restrict__ b1g,
    const float* __restrict__ bias, unsigned short* __restrict__ ub,
    float* __restrict__ slw) {
    __shared__ unsigned short As[16384] __attribute__((aligned(16)));  // 32 KB
    int n0 = blockIdx.x * 64;
    int tid = threadIdx.x;
    {
        float* sfin = (float*)As;
        float s = 0.f, q = 0.f;
#pragma unroll
        for (int cc = 0; cc < 16; ++cc) {
            s += sl[cc * 768 + tid];
            q += sl[cc * 768 + 256 + tid];
        }
        float m = s * (1.0f / N_NODES);
        float var = q * (1.0f / N_NODES) - m * m;
        float sc = g1[tid] / sqrtf(var + 1e-5f);
        sfin[tid] = sc;
        sfin[256 + tid] = b1g[tid] - m * sc;
    }
    __syncthreads();
    int kb = (tid & 31) * 8;
    float scr[8], shr[8];
    {
        const float* sfin = (const float*)As;
#pragma unroll
        for (int j = 0; j < 8; ++j) {
            scr[j] = sfin[kb + j];
            shr[j] = sfin[256 + kb + j];
        }
    }
    __syncthreads();
#pragma unroll
    for (int s = 0; s < 8; ++s) {
        int i = tid + s * 256;                    // 16B unit; 64 rows x 32 units
        int r = i >> 5, k8 = i & 31;
        short8v v = (short8v)(short)0;
        if (n0 + r < N_NODES) v = ((const short8v*)(tb + (size_t)(n0 + r) * 256))[k8];
        float f0 = fmaxf(fmaf(scr[0], bf2f((unsigned short)v[0]), shr[0]), 0.f);
        float f1 = fmaxf(fmaf(scr[1], bf2f((unsigned short)v[1]), shr[1]), 0.f);
        float f2 = fmaxf(fmaf(scr[2], bf2f((unsigned short)v[2]), shr[2]), 0.f);
        float f3 = fmaxf(fmaf(scr[3], bf2f((unsigned short)v[3]), shr[3]), 0.f);
        float f4 = fmaxf(fmaf(scr[4], bf2f((unsigned short)v[4]), shr[4]), 0.f);
        float f5 = fmaxf(fmaf(scr[5], bf2f((unsigned short)v[5]), shr[5]), 0.f);
        float f6 = fmaxf(fmaf(scr[6], bf2f((unsigned short)v[6]), shr[6]), 0.f);
        float f7 = fmaxf(fmaf(scr[7], bf2f((unsigned short)v[7]), shr[7]), 0.f);
        uint4 ov;
        ov.x = pack2(f0, f1); ov.y = pack2(f2, f3);
        ov.z = pack2(f4, f5); ov.w = pack2(f6, f7);
        int frag = (r >> 4) * 32 + k8;
        int off = (frag * 128 + (r & 15) * 8) ^ ((k8 & 7) << 3);
        *(uint4*)(&As[off]) = ov;
    }
    __syncthreads();
    int lane = threadIdx.x & 63;
    int wid = threadIdx.x >> 6;
    int l15 = lane & 15, kg = lane >> 4;
    int colbase = wid * 32;
    f32x4 acc[4][2];  // [rb][cf]
#pragma unroll
    for (int a = 0; a < 4; ++a) {
        acc[a][0] = (f32x4)(0.f);
        acc[a][1] = (f32x4)(0.f);
    }
#pragma unroll
    for (int k4 = 0; k4 < 8; ++k4) {
        short8v af[4], bf[2];
#pragma unroll
        for (int rb = 0; rb < 4; ++rb)
            af[rb] = *(const short8v*)(&As[((rb * 32 + k4 * 4 + kg) * 128 + l15 * 8) ^
                                           (((k4 * 4 + kg) & 7) << 3)]);
#pragma unroll
        for (int cf = 0; cf < 2; ++cf)
            bf[cf] = *(const short8v*)(Bp + ((k4 * 4 + kg) * 128 + colbase + cf * 16 + l15) * 8);
#pragma unroll
        for (int rb = 0; rb < 4; ++rb)
#pragma unroll
            for (int cf = 0; cf < 2; ++cf)
                acc[rb][cf] = __builtin_amdgcn_mfma_f32_16x16x32_bf16(bf[cf], af[rb],
                                                                      acc[rb][cf], 0, 0, 0);
    }
    float s4[2][4], q4[2][4];
#pragma unroll
    for (int cf = 0; cf < 2; ++cf)
#pragma unroll
        for (int r = 0; r < 4; ++r) { s4[cf][r] = 0.f; q4[cf][r] = 0.f; }
#pragma unroll
    for (int cf = 0; cf < 2; ++cf) {
        int j0 = colbase + cf * 16 + kg * 4;
        float4 b4 = *(const float4*)(bias + j0);
#pragma unroll
        for (int rb = 0; rb < 4; ++rb) {
            int gr = n0 + rb * 16 + l15;
            if (gr < N_NODES) {
                float v0 = acc[rb][cf][0] + b4.x;
                float v1 = acc[rb][cf][1] + b4.y;
                float v2 = acc[rb][cf][2] + b4.z;
                float v3 = acc[rb][cf][3] + b4.w;
                uint2 st;
                st.x = pack2(v0, v1);
                st.y = pack2(v2, v3);
                *(uint2*)(ub + (size_t)gr * 128 + j0) = st;
                s4[cf][0] += v0; q4[cf][0] += v0 * v0;
                s4[cf][1] += v1; q4[cf][1] += v1 * v1;
                s4[cf][2] += v2; q4[cf][2] += v2 * v2;
                s4[cf][3] += v3; q4[cf][3] += v3 * v3;
            }
        }
    }
    float* stats = slw + (size_t)(blockIdx.x & 15) * 768;
    float* part = (float*)As;  // need 128*16 floats = 8 KB
    __syncthreads();
#pragma unroll
    for (int cf = 0; cf < 2; ++cf)
#pragma unroll
        for (int r = 0; r < 4; ++r)
            part[(colbase + cf * 16 + kg * 4 + r) * 16 + l15] = s4[cf][r];
    __syncthreads();
    if (tid < 128) {
        const float4* pr = (const float4*)(part + tid * 16);
        float4 a0 = pr[0], a1 = pr[1], a2 = pr[2], a3 = pr[3];
        float s = a0.x + a0.y + a0.z + a0.w + a1.x + a1.y + a1.z + a1.w +
                  a2.x + a2.y + a2.z + a2.w + a3.x + a3.y + a3.z + a3.w;
        atomicAdd(&stats[512 + tid], s);
    }
    __syncthreads();
#pragma unroll
    for (int cf = 0; cf < 2; ++cf)
#pragma unroll
        for (int r = 0; r < 4; ++r)
            part[(colbase + cf * 16 + kg * 4 + r) * 16 + l15] = q4[cf][r];
    __syncthreads();
    if (tid < 128) {
        const float4* pr = (const float4*)(part + tid * 16);
        float4 a0 = pr[0], a1 = pr[1], a2 = pr[2], a3 = pr[3];
        float s = a0.x + a0.y + a0.z + a0.w + a1.x + a1.y + a1.z + a1.w +
                  a2.x + a2.y + a2.z + a2.w + a3.x + a3.y + a3.z + a3.w;
        atomicAdd(&stats[640 + tid], s);
    }
}

// --------- hb += maybe_relu(BN2(u)); grid-stride (amortized in-block BN2
// finalize). Last layer: fused node head from pre-rounding fp32 values.
__global__ __launch_bounds__(256) void k_update_h(
    unsigned short* __restrict__ hb, const unsigned short* __restrict__ ub,
    const float* __restrict__ sl,
    const float* __restrict__ g2, const float* __restrict__ b2g,
    int relu, int head,
    const int* __restrict__ batch, const float* __restrict__ nW,
    const float* __restrict__ nb, const float* __restrict__ eW,
    float* __restrict__ out, float* __restrict__ p,
    float* __restrict__ q, float* __restrict__ nsc) {
    __shared__ float sfin[256];
    if (threadIdx.x < 128) {
        int j = threadIdx.x;
        float s = 0.f, qq = 0.f;
#pragma unroll
        for (int cc = 0; cc < 16; ++cc) {
            s += sl[cc * 768 + 512 + j];
            qq += sl[cc * 768 + 640 + j];
        }
        float m = s * (1.0f / N_NODES);
        float var = qq * (1.0f / N_NODES) - m * m;
        float sc = g2[j] / sqrtf(var + 1e-5f);
        sfin[j] = sc;
        sfin[128 + j] = b2g[j] - m * sc;
    }
    __syncthreads();
    int kb = (threadIdx.x & 15) * 8;
    float scr[8], shr[8];
#pragma unroll
    for (int j = 0; j < 8; ++j) {
        scr[j] = sfin[kb + j];
        shr[j] = sfin[128 + kb + j];
    }
    float4 wn0, wn1, wa0, wa1, wb0, wb1;
    if (head) {
        wn0 = *(const float4*)(nW + kb);
        wn1 = *(const float4*)(nW + kb + 4);
        wa0 = *(const float4*)(eW + kb);
        wa1 = *(const float4*)(eW + kb + 4);
        wb0 = *(const float4*)(eW + 128 + kb);
        wb1 = *(const float4*)(eW + 128 + kb + 4);
    }
    for (int i = blockIdx.x * 256 + threadIdx.x; i < N_NODES * 16; i += UPD_BLK * 256) {
        uint4 uv = ((const uint4*)ub)[i];
        uint4 hv = ((const uint4*)hb)[i];
        float v0 = fmaf(scr[0], bf2f((unsigned short)(uv.x & 0xffffu)), shr[0]);
        float v1 = fmaf(scr[1], bf2f((unsigned short)(uv.x >> 16)), shr[1]);
        float v2 = fmaf(scr[2], bf2f((unsigned short)(uv.y & 0xffffu)), shr[2]);
        float v3 = fmaf(scr[3], bf2f((unsigned short)(uv.y >> 16)), shr[3]);
        float v4 = fmaf(scr[4], bf2f((unsigned short)(uv.z & 0xffffu)), shr[4]);
        float v5 = fmaf(scr[5], bf2f((unsigned short)(uv.z >> 16)), shr[5]);
        float v6 = fmaf(scr[6], bf2f((unsigned short)(uv.w & 0xffffu)), shr[6]);
        float v7 = fmaf(scr[7], bf2f((unsigned short)(uv.w >> 16)), shr[7]);
        if (relu) {
            v0 = fmaxf(v0, 0.f); v1 = fmaxf(v1, 0.f); v2 = fmaxf(v2, 0.f); v3 = fmaxf(v3, 0.f);
            v4 = fmaxf(v4, 0.f); v5 = fmaxf(v5, 0.f); v6 = fmaxf(v6, 0.f); v7 = fmaxf(v7, 0.f);
        }
        float h0 = bf2f((unsigned short)(hv.x & 0xffffu)) + v0;
        float h1 = bf2f((unsigned short)(hv.x >> 16)) + v1;
        float h2 = bf2f((unsigned short)(hv.y & 0xffffu)) + v2;
        float h3 = bf2f((unsigned short)(hv.y >> 16)) + v3;
        float h4 = bf2f((unsigned short)(hv.z & 0xffffu)) + v4;
        float h5 = bf2f((unsigned short)(hv.z >> 16)) + v5;
        float h6 = bf2f((unsigned short)(hv.w & 0xffffu)) + v6;
        float h7 = bf2f((unsigned short)(hv.w >> 16)) + v7;
        uint4 hp;
        hp.x = pack2(h0, h1); hp.y = pack2(h2, h3);
        hp.z = pack2(h4, h5); hp.w = pack2(h6, h7);
        ((uint4*)hb)[i] = hp;
        if (head) {
            float pn = h0 * wn0.x + h1 * wn0.y + h2 * wn0.z + h3 * wn0.w +
                       h4 * wn1.x + h5 * wn1.y + h6 * wn1.z + h7 * wn1.w;
            float pa = h0 * wa0.x + h1 * wa0.y + h2 * wa0.z + h3 * wa0.w +
                       h4 * wa1.x + h5 * wa1.y + h6 * wa1.z + h7 * wa1.w;
            float pb = h0 * wb0.x + h1 * wb0.y + h2 * wb0.z + h3 * wb0.w +
                       h4 * wb1.x + h5 * wb1.y + h6 * wb1.z + h7 * wb1.w;
#pragma unroll
            for (int off = 1; off < 16; off <<= 1) {
                pn += __shfl_xor(pn, off);
                pa += __shfl_xor(pa, off);
                pb += __shfl_xor(pb, off);
            }
            if ((threadIdx.x & 15) == 0) {
                int gr = i >> 4;
                float nk = 1.f / (1.f + expf(-(pn + nb[0])));
                out[gr] = nk;
                int g = batch[gr];
                float* base = nsc + (size_t)(blockIdx.x & 7) * 8192;
                atomicAdd(&base[g], nk);
                atomicAdd(&base[4096 + g], 1.0f - nk);
                p[gr] = pa;
                q[gr] = pb;
            }
        }
    }
}

// ------------- edge head: LDS-binned seg sums, zero global atomics.
__global__ __launch_bounds__(256) void k_edge_out(
    const int* __restrict__ ei, const int* __restrict__ batch,
    const float* __restrict__ p, const float* __restrict__ q,
    const float* __restrict__ eb, float* __restrict__ out,
    float* __restrict__ esc) {
    __shared__ float bins[8192];  // [2][4096] = 32 KB
    for (int i = threadIdx.x; i < 8192; i += 256) bins[i] = 0.f;
    __syncthreads();
    float ebv = eb[0];
    for (int e = blockIdx.x * 256 + threadIdx.x; e < N_EDGES; e += EOUT_BLK * 256) {
        int r = ei[e], c = ei[N_EDGES + e];
        float ek = 1.f / (1.f + expf(-(p[r] + q[c] + ebv)));
        out[N_NODES + e] = ek;
        int g = batch[r];
        atomicAdd(&bins[g], ek);
        atomicAdd(&bins[4096 + g], 1.0f - ek);
    }
    __syncthreads();
    float* dst = esc + (size_t)blockIdx.x * 8192;
    for (int i = threadIdx.x; i < 8192; i += 256) dst[i] = bins[i];
}

// ------------- reduce the scratch copies into the 4 output segments
__global__ void k_seg_reduce(const float* __restrict__ nsc, const float* __restrict__ esc,
                             float* __restrict__ out) {
    int i = blockIdx.x * 256 + threadIdx.x;   // 0..16383
    if (i >= 16384) return;
    float s = 1e-8f;
    if (i < 8192) {
#pragma unroll
        for (int c = 0; c < 8; ++c) s += nsc[c * 8192 + i];
    } else {
        int j = i - 8192;
        for (int c = 0; c < EOUT_BLK; ++c) s += esc[(size_t)c * 8192 + j];
    }
    out[N_NODES + N_EDGES + i] = s;
}

extern "C" void kernel_launch(void* const* d_in, const int* in_sizes, int n_in,
                              void* d_out, int out_size, void* d_ws, size_t ws_size,
                              hipStream_t stream) {
    const int*   x     = (const int*)d_in[0];
    const int*   ei    = (const int*)d_in[1];
    const int*   ea    = (const int*)d_in[2];
    const int*   batch = (const int*)d_in[3];
    const float* at    = (const float*)d_in[4];
    const float* bt    = (const float*)d_in[5];
    const float* eps   = (const float*)d_in[6];
    const float* W1    = (const float*)d_in[7];
    const float* b1    = (const float*)d_in[8];
    const float* bn1g  = (const float*)d_in[9];
    const float* bn1b  = (const float*)d_in[10];
    const float* W2    = (const float*)d_in[11];
    const float* b2    = (const float*)d_in[12];
    const float* obng  = (const float*)d_in[13];
    const float* obnb  = (const float*)d_in[14];
    const float* nW    = (const float*)d_in[15];
    const float* nb    = (const float*)d_in[16];
    const float* eW    = (const float*)d_in[17];
    const float* eb    = (const float*)d_in[18];
    float* out = (float*)d_out;

    // zero-init region (one memset): [stats 3*16*768][nsc 8*8192][cnt N]
    float* ws    = (float*)d_ws;
    float* stats = ws;                       // 36864 floats
    float* nsc   = stats + 3 * 16 * 768;     // 65536 floats
    int* cnt     = (int*)(nsc + 8 * 8192);   // N ints (counter AND cursor)
    float* p     = (float*)(cnt + N_NODES);  // N
    float* q     = p + N_NODES;              // N
    float* esc   = q + N_NODES;              // EOUT_BLK*8192 edge seg scratch (16 MB)
    unsigned short* hb  = (unsigned short*)(esc + (size_t)EOUT_BLK * 8192);  // N*128 bf16
    unsigned short* zub = hb + 12800000;     // N*128 bf16: z (gemm1 in), then u
    unsigned short* tb  = zub + 12800000;    // N*256 bf16
    unsigned short* Bp1 = tb + 25600000;     // 3*128*256 bf16
    unsigned short* Bp2 = Bp1 + 3 * 32768;   // 3*256*128 bf16
    unsigned short* ct  = Bp2 + 3 * 32768;   // 3*512*128 bf16 combined bond
    int* csr_pack = (int*)(ct + 3 * 65536);  // N*DMAX  (row<<9 | attr)
    // per-layer stats: sl = stats + l*16*768; copy c at sl + c*768:
    //   [sum256][sq256][osum128@512][osq128@640]

    hipMemsetAsync(stats, 0, (3 * 16 * 768 + 8 * 8192 + N_NODES) * 4, stream);
    // merged independent front work: atom encode + static-slot CSR fill + tables
    k_front<<<28880, 256, 0, stream>>>(x, at, hb, ei, ea, cnt, csr_pack,
                                       W1, W2, bt, Bp1, Bp2, ct);

    for (int l = 0; l < 3; ++l) {
        float* sl = stats + (size_t)l * 16 * 768;
        k_gather<<<25000, 256, 0, stream>>>(hb, csr_pack, cnt,
                                            ct + (size_t)l * 65536, eps, l, zub);
        k_gemm1<<<1563, 256, 0, stream>>>(zub, Bp1 + (size_t)l * 32768, b1 + l * 256, tb, sl);
        k_gemm2<<<1563, 256, 0, stream>>>(tb, Bp2 + (size_t)l * 32768, sl,
                                          bn1g + l * 256, bn1b + l * 256,
                                          b2 + l * 128, zub, sl);
        k_update_h<<<UPD_BLK, 256, 0, stream>>>(hb, zub, sl, obng + l * 128, obnb + l * 128,
                                                (l < 2) ? 1 : 0, (l == 2) ? 1 : 0,
                                                batch, nW, nb, eW, out, p, q, nsc);
    }

    k_edge_out<<<EOUT_BLK, 256, 0, stream>>>(ei, batch, p, q, eb, out, esc);
    k_seg_reduce<<<64, 256, 0, stream>>>(nsc, esc, out);
}

// Round 18
// 440.943 us; speedup vs baseline: 7.8705x; 1.0126x over previous
//
#include <hip/hip_runtime.h>
#include <math.h>

#define N_NODES 100000
#define N_EDGES 600000
#define N_GRAPHS 4096
#define DMAX 32         // static CSR slot capacity (P(deg>=32) ~ 1e-13/node)
#define EOUT_BLK 512    // edge_out grid (LDS-binned, scratch copies)
#define UPD_BLK 2048    // update_h grid (grid-stride, amortized BN2 finalize)

// front grid partition
#define FR_ATOM 12500                 // 2 nodes/wave, 4 waves/block -> 8 nodes/blk
#define FR_FILL 1172                  // 2 edges/thread
#define FR_PREP 1536
#define FR_TOTAL (FR_ATOM + FR_FILL + FR_PREP)

typedef __attribute__((ext_vector_type(8))) short short8v;   // 8 bf16 (4 VGPR)
typedef __attribute__((ext_vector_type(4))) float f32x4;

// fp32 pair -> packed bf16 (RNE) via the HW instruction
__device__ __forceinline__ unsigned int pack2(float a, float b) {
    unsigned int r;
    asm("v_cvt_pk_bf16_f32 %0, %1, %2" : "=v"(r) : "v"(a), "v"(b));
    return r;
}
__device__ __forceinline__ unsigned short bf16_rne(float f) {
    unsigned int r;
    asm("v_cvt_pk_bf16_f32 %0, %1, %2" : "=v"(r) : "v"(f), "v"(f));
    return (unsigned short)r;
}
__device__ __forceinline__ float bf2f(unsigned short u) {
    return __uint_as_float(((unsigned int)u) << 16);
}

// ------ merged front: three INDEPENDENT one-time jobs in one dispatch:
//   blocks [0,FR_ATOM)    atom encoder (2 nodes per wave, scalarized x-rows)
//   next FR_FILL blocks   static-slot CSR fill, 2 edges/thread
//   next FR_PREP blocks   weight pre-swizzle + combined bond table
__global__ void k_front(const int* __restrict__ x, const float* __restrict__ at,
                        unsigned short* __restrict__ hb,
                        const int* __restrict__ ei, const int* __restrict__ ea,
                        int* __restrict__ cnt, int* __restrict__ csr_pack,
                        const float* __restrict__ W1, const float* __restrict__ W2,
                        const float* __restrict__ bt,
                        unsigned short* __restrict__ Bp1, unsigned short* __restrict__ Bp2,
                        unsigned short* __restrict__ ct) {
    if (blockIdx.x < FR_ATOM) {
        int lane = threadIdx.x & 63;
        int n0 = blockIdx.x * 8 + (threadIdx.x >> 6) * 2;
#pragma unroll
        for (int t = 0; t < 2; ++t) {
            int n = __builtin_amdgcn_readfirstlane(n0 + t);
            const int* xr = x + n * 9;
            float sx = 0.f, sy = 0.f;
#pragma unroll
            for (int f = 0; f < 9; ++f) {
                int v = __builtin_amdgcn_readfirstlane(xr[f]);
                float2 tv = ((const float2*)(at + (f * 100 + v) * 128))[lane];
                sx += tv.x;
                sy += tv.y;
            }
            ((unsigned int*)(hb + ((size_t)n << 7)))[lane] = pack2(sx, sy);
        }
    } else if (blockIdx.x < FR_ATOM + FR_FILL) {
        int base = ((blockIdx.x - FR_ATOM) * 256 + threadIdx.x) * 2;
#pragma unroll
        for (int t = 0; t < 2; ++t) {
            int e = base + t;
            if (e < N_EDGES) {
                int c = ei[N_EDGES + e];
                int pos = atomicAdd(&cnt[c], 1);
                if (pos < DMAX) {
                    int attr = ea[e * 3] * 64 + ea[e * 3 + 1] * 8 + ea[e * 3 + 2];
                    csr_pack[((size_t)c << 5) + pos] = (ei[e] << 9) | attr;
                }
            }
        }
    } else {
        int pb = blockIdx.x - FR_ATOM - FR_FILL;
        if (pb < 768) {
            int idx = pb * 256 + threadIdx.x;
            if (idx < 3 * 128 * 256) {
                int l = idx >> 15, r = idx & 32767;
                int k = r >> 8, j = r & 255;
                float v = W1[(size_t)l * 32768 + k * 256 + j];
                Bp1[(size_t)l * 32768 +
                    (((k >> 5) * 4 + ((k >> 3) & 3)) * 256 + j) * 8 + (k & 7)] = bf16_rne(v);
            } else if (idx < 6 * 128 * 256) {
                int t = idx - 98304;
                int l = t >> 15, r = t & 32767;
                int k = r >> 7, j = r & 127;
                float v = W2[(size_t)l * 32768 + k * 128 + j];
                Bp2[(size_t)l * 32768 +
                    (((k >> 5) * 4 + ((k >> 3) & 3)) * 128 + j) * 8 + (k & 7)] = bf16_rne(v);
            }
        } else {
            int idx = (pb - 768) * 256 + threadIdx.x;
            if (idx >= 3 * 512 * 128) return;
            int d = idx & 127;
            int c = (idx >> 7) & 511;
            int l = idx >> 16;
            const float* base = bt + (size_t)l * 3072;
            float v = base[(c >> 6) * 128 + d] + base[1024 + ((c >> 3) & 7) * 128 + d] +
                      base[2048 + (c & 7) * 128 + d];
            ct[idx] = bf16_rne(v);
        }
    }
}

// ---------------------------- gather-aggregate: z = (1+eps)*h + sum relu(msg)
// wave per node; static-slot CSR (base n*32, deg from cnt); scalarized index
// stream; self-load hoisted; 4/2/1 tail
#define EDGE2(uu, cc)                                                          \
    {                                                                          \
        ax += fmaxf(bf2f((unsigned short)((uu) & 0xffffu)) +                   \
                    bf2f((unsigned short)((cc) & 0xffffu)), 0.f);              \
        ay += fmaxf(bf2f((unsigned short)((uu) >> 16)) +                       \
                    bf2f((unsigned short)((cc) >> 16)), 0.f);                  \
    }

__global__ void k_gather(const unsigned short* __restrict__ hb,
                         const int* __restrict__ csr_pack, const int* __restrict__ cnt,
                         const unsigned short* __restrict__ ct,
                         const float* __restrict__ eps, int l,
                         unsigned short* __restrict__ zb) {
    int lane = threadIdx.x & 63;
    int n = blockIdx.x * 4 + (threadIdx.x >> 6);
    if (n >= N_NODES) return;
    n = __builtin_amdgcn_readfirstlane(n);
    int deg = __builtin_amdgcn_readfirstlane(cnt[n]);
    deg = min(deg, DMAX);
    const int* row = csr_pack + ((size_t)n << 5);
    unsigned int un = ((const unsigned int*)(hb + ((size_t)n << 7)))[lane];
    float ax = 0.f, ay = 0.f;
    int i = 0;
    for (; i + 4 <= deg; i += 4) {
        int rc0 = __builtin_amdgcn_readfirstlane(row[i]);
        int rc1 = __builtin_amdgcn_readfirstlane(row[i + 1]);
        int rc2 = __builtin_amdgcn_readfirstlane(row[i + 2]);
        int rc3 = __builtin_amdgcn_readfirstlane(row[i + 3]);
        unsigned int u0 = ((const unsigned int*)(hb + ((size_t)(rc0 >> 9) << 7)))[lane];
        unsigned int u1 = ((const unsigned int*)(hb + ((size_t)(rc1 >> 9) << 7)))[lane];
        unsigned int u2 = ((const unsigned int*)(hb + ((size_t)(rc2 >> 9) << 7)))[lane];
        unsigned int u3 = ((const unsigned int*)(hb + ((size_t)(rc3 >> 9) << 7)))[lane];
        unsigned int c0 = ((const unsigned int*)(ct + ((rc0 & 511) << 7)))[lane];
        unsigned int c1 = ((const unsigned int*)(ct + ((rc1 & 511) << 7)))[lane];
        unsigned int c2 = ((const unsigned int*)(ct + ((rc2 & 511) << 7)))[lane];
        unsigned int c3 = ((const unsigned int*)(ct + ((rc3 & 511) << 7)))[lane];
        EDGE2(u0, c0); EDGE2(u1, c1); EDGE2(u2, c2); EDGE2(u3, c3);
    }
    if (i + 2 <= deg) {
        int rc0 = __builtin_amdgcn_readfirstlane(row[i]);
        int rc1 = __builtin_amdgcn_readfirstlane(row[i + 1]);
        unsigned int u0 = ((const unsigned int*)(hb + ((size_t)(rc0 >> 9) << 7)))[lane];
        unsigned int u1 = ((const unsigned int*)(hb + ((size_t)(rc1 >> 9) << 7)))[lane];
        unsigned int c0 = ((const unsigned int*)(ct + ((rc0 & 511) << 7)))[lane];
        unsigned int c1 = ((const unsigned int*)(ct + ((rc1 & 511) << 7)))[lane];
        EDGE2(u0, c0); EDGE2(u1, c1);
        i += 2;
    }
    if (i < deg) {
        int rc0 = __builtin_amdgcn_readfirstlane(row[i]);
        unsigned int u0 = ((const unsigned int*)(hb + ((size_t)(rc0 >> 9) << 7)))[lane];
        unsigned int c0 = ((const unsigned int*)(ct + ((rc0 & 511) << 7)))[lane];
        EDGE2(u0, c0);
    }
    float el = 1.0f + eps[l];
    float zx = fmaf(el, bf2f((unsigned short)(un & 0xffffu)), ax);
    float zy = fmaf(el, bf2f((unsigned short)(un >> 16)), ay);
    ((unsigned int*)(zb + ((size_t)n << 7)))[lane] = pack2(zx, zy);
}

// --------------------- GEMM1 (MFMA, swapped operands -> (z@W1)^T fragments)
// stats partials go to 16 spread copies (sl[(bid&15)*768 + ...])
__global__ __launch_bounds__(256) void k_gemm1(
    const unsigned short* __restrict__ zb, const unsigned short* __restrict__ Bp,
    const float* __restrict__ bias, unsigned short* __restrict__ tb,
    float* __restrict__ sl) {
    __shared__ unsigned short As[8192] __attribute__((aligned(16)));  // 16 KB
    int n0 = blockIdx.x * 64;
#pragma unroll
    for (int s = 0; s < 4; ++s) {
        int i = threadIdx.x + s * 256;            // 16B unit; 64 rows x 16 units
        int r = i >> 4, k8 = i & 15;
        short8v v = (short8v)(short)0;
        if (n0 + r < N_NODES) v = ((const short8v*)(zb + (size_t)(n0 + r) * 128))[k8];
        int frag = (r >> 4) * 16 + k8;
        int off = (frag * 128 + (r & 15) * 8) ^ ((k8 & 7) << 3);
        *(short8v*)(&As[off]) = v;
    }
    __syncthreads();
    int lane = threadIdx.x & 63;
    int wid = threadIdx.x >> 6;
    int l15 = lane & 15, kg = lane >> 4;
    int colbase = wid * 64;
    f32x4 acc[4][4];  // [rb][cf]
#pragma unroll
    for (int a = 0; a < 4; ++a)
#pragma unroll
        for (int b = 0; b < 4; ++b) acc[a][b] = (f32x4)(0.f);
#pragma unroll
    for (int k4 = 0; k4 < 4; ++k4) {
        short8v af[4], bf[4];
#pragma unroll
        for (int rb = 0; rb < 4; ++rb)
            af[rb] = *(const short8v*)(&As[((rb * 16 + k4 * 4 + kg) * 128 + l15 * 8) ^
                                           (((k4 * 4 + kg) & 7) << 3)]);
#pragma unroll
        for (int cf = 0; cf < 4; ++cf)
            bf[cf] = *(const short8v*)(Bp + ((k4 * 4 + kg) * 256 + colbase + cf * 16 + l15) * 8);
#pragma unroll
        for (int rb = 0; rb < 4; ++rb)
#pragma unroll
            for (int cf = 0; cf < 4; ++cf)
                acc[rb][cf] = __builtin_amdgcn_mfma_f32_16x16x32_bf16(bf[cf], af[rb],
                                                                      acc[rb][cf], 0, 0, 0);
    }
    float s4[4][4], q4[4][4];
#pragma unroll
    for (int cf = 0; cf < 4; ++cf)
#pragma unroll
        for (int r = 0; r < 4; ++r) { s4[cf][r] = 0.f; q4[cf][r] = 0.f; }
#pragma unroll
    for (int cf = 0; cf < 4; ++cf) {
        int j0 = colbase + cf * 16 + kg * 4;
        float4 b4 = *(const float4*)(bias + j0);
#pragma unroll
        for (int rb = 0; rb < 4; ++rb) {
            int gr = n0 + rb * 16 + l15;
            if (gr < N_NODES) {
                float v0 = acc[rb][cf][0] + b4.x;
                float v1 = acc[rb][cf][1] + b4.y;
                float v2 = acc[rb][cf][2] + b4.z;
                float v3 = acc[rb][cf][3] + b4.w;
                uint2 st;
                st.x = pack2(v0, v1);
                st.y = pack2(v2, v3);
                *(uint2*)(tb + (size_t)gr * 256 + j0) = st;
                s4[cf][0] += v0; q4[cf][0] += v0 * v0;
                s4[cf][1] += v1; q4[cf][1] += v1 * v1;
                s4[cf][2] += v2; q4[cf][2] += v2 * v2;
                s4[cf][3] += v3; q4[cf][3] += v3 * v3;
            }
        }
    }
    float* stats = sl + (size_t)(blockIdx.x & 15) * 768;
    float* part = (float*)As;
    __syncthreads();
#pragma unroll
    for (int cf = 0; cf < 4; ++cf)
#pragma unroll
        for (int r = 0; r < 4; ++r)
            part[(colbase + cf * 16 + kg * 4 + r) * 16 + l15] = s4[cf][r];
    __syncthreads();
    {
        int j = threadIdx.x;
        const float4* pr = (const float4*)(part + j * 16);
        float4 a0 = pr[0], a1 = pr[1], a2 = pr[2], a3 = pr[3];
        float s = a0.x + a0.y + a0.z + a0.w + a1.x + a1.y + a1.z + a1.w +
                  a2.x + a2.y + a2.z + a2.w + a3.x + a3.y + a3.z + a3.w;
        atomicAdd(&stats[j], s);
    }
    __syncthreads();
#pragma unroll
    for (int cf = 0; cf < 4; ++cf)
#pragma unroll
        for (int r = 0; r < 4; ++r)
            part[(colbase + cf * 16 + kg * 4 + r) * 16 + l15] = q4[cf][r];
    __syncthreads();
    {
        int j = threadIdx.x;
        const float4* pr = (const float4*)(part + j * 16);
        float4 a0 = pr[0], a1 = pr[1], a2 = pr[2], a3 = pr[3];
        float s = a0.x + a0.y + a0.z + a0.w + a1.x + a1.y + a1.z + a1.w +
                  a2.x + a2.y + a2.z + a2.w + a3.x + a3.y + a3.z + a3.w;
        atomicAdd(&stats[256 + j], s);
    }
}

// ------- GEMM2 (MFMA, swapped): u = relu(BN1(t))@W2 + b2, fused BN2 stats
// BN1 finalize done in-block: sum 16 spread copies -> LDS -> regs
__global__ __launch_bounds__(256) void k_gemm2(
    const unsigned short* __restrict__ tb, const unsigned short* __restrict__ Bp,
    const float* __restrict__ sl, const float* __restrict__ g1,
    const float* __restrict__ b1g,
    const float* __restrict__ bias, unsigned short* __restrict__ ub,
    float* __restrict__ slw) {
    __shared__ unsigned short As[16384] __attribute__((aligned(16)));  // 32 KB
    int n0 = blockIdx.x * 64;
    int tid = threadIdx.x;
    {
        float* sfin = (float*)As;
        float s = 0.f, q = 0.f;
#pragma unroll
        for (int cc = 0; cc < 16; ++cc) {
            s += sl[cc * 768 + tid];
            q += sl[cc * 768 + 256 + tid];
        }
        float m = s * (1.0f / N_NODES);
        float var = q * (1.0f / N_NODES) - m * m;
        float sc = g1[tid] / sqrtf(var + 1e-5f);
        sfin[tid] = sc;
        sfin[256 + tid] = b1g[tid] - m * sc;
    }
    __syncthreads();
    int kb = (tid & 31) * 8;
    float scr[8], shr[8];
    {
        const float* sfin = (const float*)As;
#pragma unroll
        for (int j = 0; j < 8; ++j) {
            scr[j] = sfin[kb + j];
            shr[j] = sfin[256 + kb + j];
        }
    }
    __syncthreads();
#pragma unroll
    for (int s = 0; s < 8; ++s) {
        int i = tid + s * 256;                    // 16B unit; 64 rows x 32 units
        int r = i >> 5, k8 = i & 31;
        short8v v = (short8v)(short)0;
        if (n0 + r < N_NODES) v = ((const short8v*)(tb + (size_t)(n0 + r) * 256))[k8];
        float f0 = fmaxf(fmaf(scr[0], bf2f((unsigned short)v[0]), shr[0]), 0.f);
        float f1 = fmaxf(fmaf(scr[1], bf2f((unsigned short)v[1]), shr[1]), 0.f);
        float f2 = fmaxf(fmaf(scr[2], bf2f((unsigned short)v[2]), shr[2]), 0.f);
        float f3 = fmaxf(fmaf(scr[3], bf2f((unsigned short)v[3]), shr[3]), 0.f);
        float f4 = fmaxf(fmaf(scr[4], bf2f((unsigned short)v[4]), shr[4]), 0.f);
        float f5 = fmaxf(fmaf(scr[5], bf2f((unsigned short)v[5]), shr[5]), 0.f);
        float f6 = fmaxf(fmaf(scr[6], bf2f((unsigned short)v[6]), shr[6]), 0.f);
        float f7 = fmaxf(fmaf(scr[7], bf2f((unsigned short)v[7]), shr[7]), 0.f);
        uint4 ov;
        ov.x = pack2(f0, f1); ov.y = pack2(f2, f3);
        ov.z = pack2(f4, f5); ov.w = pack2(f6, f7);
        int frag = (r >> 4) * 32 + k8;
        int off = (frag * 128 + (r & 15) * 8) ^ ((k8 & 7) << 3);
        *(uint4*)(&As[off]) = ov;
    }
    __syncthreads();
    int lane = threadIdx.x & 63;
    int wid = threadIdx.x >> 6;
    int l15 = lane & 15, kg = lane >> 4;
    int colbase = wid * 32;
    f32x4 acc[4][2];  // [rb][cf]
#pragma unroll
    for (int a = 0; a < 4; ++a) {
        acc[a][0] = (f32x4)(0.f);
        acc[a][1] = (f32x4)(0.f);
    }
#pragma unroll
    for (int k4 = 0; k4 < 8; ++k4) {
        short8v af[4], bf[2];
#pragma unroll
        for (int rb = 0; rb < 4; ++rb)
            af[rb] = *(const short8v*)(&As[((rb * 32 + k4 * 4 + kg) * 128 + l15 * 8) ^
                                           (((k4 * 4 + kg) & 7) << 3)]);
#pragma unroll
        for (int cf = 0; cf < 2; ++cf)
            bf[cf] = *(const short8v*)(Bp + ((k4 * 4 + kg) * 128 + colbase + cf * 16 + l15) * 8);
#pragma unroll
        for (int rb = 0; rb < 4; ++rb)
#pragma unroll
            for (int cf = 0; cf < 2; ++cf)
                acc[rb][cf] = __builtin_amdgcn_mfma_f32_16x16x32_bf16(bf[cf], af[rb],
                                                                      acc[rb][cf], 0, 0, 0);
    }
    float s4[2][4], q4[2][4];
#pragma unroll
    for (int cf = 0; cf < 2; ++cf)
#pragma unroll
        for (int r = 0; r < 4; ++r) { s4[cf][r] = 0.f; q4[cf][r] = 0.f; }
#pragma unroll
    for (int cf = 0; cf < 2; ++cf) {
        int j0 = colbase + cf * 16 + kg * 4;
        float4 b4 = *(const float4*)(bias + j0);
#pragma unroll
        for (int rb = 0; rb < 4; ++rb) {
            int gr = n0 + rb * 16 + l15;
            if (gr < N_NODES) {
                float v0 = acc[rb][cf][0] + b4.x;
                float v1 = acc[rb][cf][1] + b4.y;
                float v2 = acc[rb][cf][2] + b4.z;
                float v3 = acc[rb][cf][3] + b4.w;
                uint2 st;
                st.x = pack2(v0, v1);
                st.y = pack2(v2, v3);
                *(uint2*)(ub + (size_t)gr * 128 + j0) = st;
                s4[cf][0] += v0; q4[cf][0] += v0 * v0;
                s4[cf][1] += v1; q4[cf][1] += v1 * v1;
                s4[cf][2] += v2; q4[cf][2] += v2 * v2;
                s4[cf][3] += v3; q4[cf][3] += v3 * v3;
            }
        }
    }
    float* stats = slw + (size_t)(blockIdx.x & 15) * 768;
    float* part = (float*)As;  // need 128*16 floats = 8 KB
    __syncthreads();
#pragma unroll
    for (int cf = 0; cf < 2; ++cf)
#pragma unroll
        for (int r = 0; r < 4; ++r)
            part[(colbase + cf * 16 + kg * 4 + r) * 16 + l15] = s4[cf][r];
    __syncthreads();
    if (tid < 128) {
        const float4* pr = (const float4*)(part + tid * 16);
        float4 a0 = pr[0], a1 = pr[1], a2 = pr[2], a3 = pr[3];
        float s = a0.x + a0.y + a0.z + a0.w + a1.x + a1.y + a1.z + a1.w +
                  a2.x + a2.y + a2.z + a2.w + a3.x + a3.y + a3.z + a3.w;
        atomicAdd(&stats[512 + tid], s);
    }
    __syncthreads();
#pragma unroll
    for (int cf = 0; cf < 2; ++cf)
#pragma unroll
        for (int r = 0; r < 4; ++r)
            part[(colbase + cf * 16 + kg * 4 + r) * 16 + l15] = q4[cf][r];
    __syncthreads();
    if (tid < 128) {
        const float4* pr = (const float4*)(part + tid * 16);
        float4 a0 = pr[0], a1 = pr[1], a2 = pr[2], a3 = pr[3];
        float s = a0.x + a0.y + a0.z + a0.w + a1.x + a1.y + a1.z + a1.w +
                  a2.x + a2.y + a2.z + a2.w + a3.x + a3.y + a3.z + a3.w;
        atomicAdd(&stats[640 + tid], s);
    }
}

// --------- hb += maybe_relu(BN2(u)); grid-stride (amortized in-block BN2
// finalize). Last layer: fused node head from pre-rounding fp32 values.
__global__ __launch_bounds__(256) void k_update_h(
    unsigned short* __restrict__ hb, const unsigned short* __restrict__ ub,
    const float* __restrict__ sl,
    const float* __restrict__ g2, const float* __restrict__ b2g,
    int relu, int head,
    const int* __restrict__ batch, const float* __restrict__ nW,
    const float* __restrict__ nb, const float* __restrict__ eW,
    float* __restrict__ out, float* __restrict__ p,
    float* __restrict__ q, float* __restrict__ nsc) {
    __shared__ float sfin[256];
    if (threadIdx.x < 128) {
        int j = threadIdx.x;
        float s = 0.f, qq = 0.f;
#pragma unroll
        for (int cc = 0; cc < 16; ++cc) {
            s += sl[cc * 768 + 512 + j];
            qq += sl[cc * 768 + 640 + j];
        }
        float m = s * (1.0f / N_NODES);
        float var = qq * (1.0f / N_NODES) - m * m;
        float sc = g2[j] / sqrtf(var + 1e-5f);
        sfin[j] = sc;
        sfin[128 + j] = b2g[j] - m * sc;
    }
    __syncthreads();
    int kb = (threadIdx.x & 15) * 8;
    float scr[8], shr[8];
#pragma unroll
    for (int j = 0; j < 8; ++j) {
        scr[j] = sfin[kb + j];
        shr[j] = sfin[128 + kb + j];
    }
    float4 wn0, wn1, wa0, wa1, wb0, wb1;
    if (head) {
        wn0 = *(const float4*)(nW + kb);
        wn1 = *(const float4*)(nW + kb + 4);
        wa0 = *(const float4*)(eW + kb);
        wa1 = *(const float4*)(eW + kb + 4);
        wb0 = *(const float4*)(eW + 128 + kb);
        wb1 = *(const float4*)(eW + 128 + kb + 4);
    }
    for (int i = blockIdx.x * 256 + threadIdx.x; i < N_NODES * 16; i += UPD_BLK * 256) {
        uint4 uv = ((const uint4*)ub)[i];
        uint4 hv = ((const uint4*)hb)[i];
        float v0 = fmaf(scr[0], bf2f((unsigned short)(uv.x & 0xffffu)), shr[0]);
        float v1 = fmaf(scr[1], bf2f((unsigned short)(uv.x >> 16)), shr[1]);
        float v2 = fmaf(scr[2], bf2f((unsigned short)(uv.y & 0xffffu)), shr[2]);
        float v3 = fmaf(scr[3], bf2f((unsigned short)(uv.y >> 16)), shr[3]);
        float v4 = fmaf(scr[4], bf2f((unsigned short)(uv.z & 0xffffu)), shr[4]);
        float v5 = fmaf(scr[5], bf2f((unsigned short)(uv.z >> 16)), shr[5]);
        float v6 = fmaf(scr[6], bf2f((unsigned short)(uv.w & 0xffffu)), shr[6]);
        float v7 = fmaf(scr[7], bf2f((unsigned short)(uv.w >> 16)), shr[7]);
        if (relu) {
            v0 = fmaxf(v0, 0.f); v1 = fmaxf(v1, 0.f); v2 = fmaxf(v2, 0.f); v3 = fmaxf(v3, 0.f);
            v4 = fmaxf(v4, 0.f); v5 = fmaxf(v5, 0.f); v6 = fmaxf(v6, 0.f); v7 = fmaxf(v7, 0.f);
        }
        float h0 = bf2f((unsigned short)(hv.x & 0xffffu)) + v0;
        float h1 = bf2f((unsigned short)(hv.x >> 16)) + v1;
        float h2 = bf2f((unsigned short)(hv.y & 0xffffu)) + v2;
        float h3 = bf2f((unsigned short)(hv.y >> 16)) + v3;
        float h4 = bf2f((unsigned short)(hv.z & 0xffffu)) + v4;
        float h5 = bf2f((unsigned short)(hv.z >> 16)) + v5;
        float h6 = bf2f((unsigned short)(hv.w & 0xffffu)) + v6;
        float h7 = bf2f((unsigned short)(hv.w >> 16)) + v7;
        uint4 hp;
        hp.x = pack2(h0, h1); hp.y = pack2(h2, h3);
        hp.z = pack2(h4, h5); hp.w = pack2(h6, h7);
        ((uint4*)hb)[i] = hp;
        if (head) {
            float pn = h0 * wn0.x + h1 * wn0.y + h2 * wn0.z + h3 * wn0.w +
                       h4 * wn1.x + h5 * wn1.y + h6 * wn1.z + h7 * wn1.w;
            float pa = h0 * wa0.x + h1 * wa0.y + h2 * wa0.z + h3 * wa0.w +
                       h4 * wa1.x + h5 * wa1.y + h6 * wa1.z + h7 * wa1.w;
            float pb = h0 * wb0.x + h1 * wb0.y + h2 * wb0.z + h3 * wb0.w +
                       h4 * wb1.x + h5 * wb1.y + h6 * wb1.z + h7 * wb1.w;
#pragma unroll
            for (int off = 1; off < 16; off <<= 1) {
                pn += __shfl_xor(pn, off);
                pa += __shfl_xor(pa, off);
                pb += __shfl_xor(pb, off);
            }
            if ((threadIdx.x & 15) == 0) {
                int gr = i >> 4;
                float nk = 1.f / (1.f + expf(-(pn + nb[0])));
                out[gr] = nk;
                int g = batch[gr];
                float* base = nsc + (size_t)(blockIdx.x & 7) * 8192;
                atomicAdd(&base[g], nk);
                atomicAdd(&base[4096 + g], 1.0f - nk);
                p[gr] = pa;
                q[gr] = pb;
            }
        }
    }
}

// ------------- edge head: LDS-binned seg sums, zero global atomics.
__global__ __launch_bounds__(256) void k_edge_out(
    const int* __restrict__ ei, const int* __restrict__ batch,
    const float* __restrict__ p, const float* __restrict__ q,
    const float* __restrict__ eb, float* __restrict__ out,
    float* __restrict__ esc) {
    __shared__ float bins[8192];  // [2][4096] = 32 KB
    for (int i = threadIdx.x; i < 8192; i += 256) bins[i] = 0.f;
    __syncthreads();
    float ebv = eb[0];
    for (int e = blockIdx.x * 256 + threadIdx.x; e < N_EDGES; e += EOUT_BLK * 256) {
        int r = ei[e], c = ei[N_EDGES + e];
        float ek = 1.f / (1.f + expf(-(p[r] + q[c] + ebv)));
        out[N_NODES + e] = ek;
        int g = batch[r];
        atomicAdd(&bins[g], ek);
        atomicAdd(&bins[4096 + g], 1.0f - ek);
    }
    __syncthreads();
    float* dst = esc + (size_t)blockIdx.x * 8192;
    for (int i = threadIdx.x; i < 8192; i += 256) dst[i] = bins[i];
}

// ------------- reduce the scratch copies into the 4 output segments
__global__ void k_seg_reduce(const float* __restrict__ nsc, const float* __restrict__ esc,
                             float* __restrict__ out) {
    int i = blockIdx.x * 256 + threadIdx.x;   // 0..16383
    if (i >= 16384) return;
    float s = 1e-8f;
    if (i < 8192) {
#pragma unroll
        for (int c = 0; c < 8; ++c) s += nsc[c * 8192 + i];
    } else {
        int j = i - 8192;
        for (int c = 0; c < EOUT_BLK; ++c) s += esc[(size_t)c * 8192 + j];
    }
    out[N_NODES + N_EDGES + i] = s;
}

extern "C" void kernel_launch(void* const* d_in, const int* in_sizes, int n_in,
                              void* d_out, int out_size, void* d_ws, size_t ws_size,
                              hipStream_t stream) {
    const int*   x     = (const int*)d_in[0];
    const int*   ei    = (const int*)d_in[1];
    const int*   ea    = (const int*)d_in[2];
    const int*   batch = (const int*)d_in[3];
    const float* at    = (const float*)d_in[4];
    const float* bt    = (const float*)d_in[5];
    const float* eps   = (const float*)d_in[6];
    const float* W1    = (const float*)d_in[7];
    const float* b1    = (const float*)d_in[8];
    const float* bn1g  = (const float*)d_in[9];
    const float* bn1b  = (const float*)d_in[10];
    const float* W2    = (const float*)d_in[11];
    const float* b2    = (const float*)d_in[12];
    const float* obng  = (const float*)d_in[13];
    const float* obnb  = (const float*)d_in[14];
    const float* nW    = (const float*)d_in[15];
    const float* nb    = (const float*)d_in[16];
    const float* eW    = (const float*)d_in[17];
    const float* eb    = (const float*)d_in[18];
    float* out = (float*)d_out;

    // zero-init region (one memset): [stats 3*16*768][nsc 8*8192][cnt N]
    float* ws    = (float*)d_ws;
    float* stats = ws;                       // 36864 floats
    float* nsc   = stats + 3 * 16 * 768;     // 65536 floats
    int* cnt     = (int*)(nsc + 8 * 8192);   // N ints (counter AND cursor)
    float* p     = (float*)(cnt + N_NODES);  // N
    float* q     = p + N_NODES;              // N
    float* esc   = q + N_NODES;              // EOUT_BLK*8192 edge seg scratch (16 MB)
    unsigned short* hb  = (unsigned short*)(esc + (size_t)EOUT_BLK * 8192);  // N*128 bf16
    unsigned short* zub = hb + 12800000;     // N*128 bf16: z (gemm1 in), then u
    unsigned short* tb  = zub + 12800000;    // N*256 bf16
    unsigned short* Bp1 = tb + 25600000;     // 3*128*256 bf16
    unsigned short* Bp2 = Bp1 + 3 * 32768;   // 3*256*128 bf16
    unsigned short* ct  = Bp2 + 3 * 32768;   // 3*512*128 bf16 combined bond
    int* csr_pack = (int*)(ct + 3 * 65536);  // N*DMAX  (row<<9 | attr)
    // per-layer stats: sl = stats + l*16*768; copy c at sl + c*768:
    //   [sum256][sq256][osum128@512][osq128@640]

    hipMemsetAsync(stats, 0, (3 * 16 * 768 + 8 * 8192 + N_NODES) * 4, stream);
    // merged independent front work: atom encode + static-slot CSR fill + tables
    k_front<<<FR_TOTAL, 256, 0, stream>>>(x, at, hb, ei, ea, cnt, csr_pack,
                                          W1, W2, bt, Bp1, Bp2, ct);

    for (int l = 0; l < 3; ++l) {
        float* sl = stats + (size_t)l * 16 * 768;
        k_gather<<<25000, 256, 0, stream>>>(hb, csr_pack, cnt,
                                            ct + (size_t)l * 65536, eps, l, zub);
        k_gemm1<<<1563, 256, 0, stream>>>(zub, Bp1 + (size_t)l * 32768, b1 + l * 256, tb, sl);
        k_gemm2<<<1563, 256, 0, stream>>>(tb, Bp2 + (size_t)l * 32768, sl,
                                          bn1g + l * 256, bn1b + l * 256,
                                          b2 + l * 128, zub, sl);
        k_update_h<<<UPD_BLK, 256, 0, stream>>>(hb, zub, sl, obng + l * 128, obnb + l * 128,
                                                (l < 2) ? 1 : 0, (l == 2) ? 1 : 0,
                                                batch, nW, nb, eW, out, p, q, nsc);
    }

    k_edge_out<<<EOUT_BLK, 256, 0, stream>>>(ei, batch, p, q, eb, out, esc);
    k_seg_reduce<<<64, 256, 0, stream>>>(nsc, esc, out);
}